// Round 2
// baseline (328.461 us; speedup 1.0000x reference)
//
#include <hip/hip_runtime.h>

typedef __attribute__((ext_vector_type(8))) short short8;
typedef __attribute__((ext_vector_type(4))) float f32x4;

constexpr int NN = 10000;
constexpr int NE = 160000;
constexpr float EPSV = 1e-5f;
constexpr float INV3 = 0.57735026918962576f;   // 1/sqrt(3)
constexpr float ALPHA = 0.20412414523193152f;  // 1/sqrt(16+8)

__device__ __forceinline__ ushort f2bf(float x) {
  unsigned u = __float_as_uint(x);
  u += 0x7fffu + ((u >> 16) & 1u);   // round-nearest-even
  return (ushort)(u >> 16);
}

__device__ __forceinline__ f32x4 mfma16(short8 a, short8 b, f32x4 c) {
  return __builtin_amdgcn_mfma_f32_16x16x32_bf16(a, b, c, 0, 0, 0);
}

// ---------------- K1: h = relu(ef @ W1 + b1), emitted as bf16 B-fragments ----------------
// Fragment convention (both operands use the same k-order, so any hw k-permutation cancels):
//   A-frag lane(g,c) elem j : A[row=c][k=8g+j]
//   B-frag lane(g,c) elem j : B[k=8g+j][col=c]
//   C/D    lane(g,c) reg q  : D[row=4g+q][col=c]   (HW-verified layout)
// Global h-frag layout: hfrag[(tile*2+kc)*64 + lane] = 8 bf16 = h[tile*16+c][kc*32+8g+0..7]
__global__ __launch_bounds__(256) void mlp1_kernel(
    const float* __restrict__ ef, const float* __restrict__ w1,
    const float* __restrict__ b1, short8* __restrict__ hfrag,
    float* __restrict__ efout, int do_copy)
{
  __shared__ short8 w1f[512];          // W1 B-frags: [(nt*2+kc)*64 + lane]
  __shared__ ushort hlds[4][16 * 72];  // per-wave transpose buffer, pad 72

  for (int t = threadIdx.x; t < 512; t += 256) {
    int tile = t >> 6, l = t & 63;
    int nt = tile >> 1, kc = tile & 1;
    int gg = l >> 4, cc = l & 15;
    short8 v;
#pragma unroll
    for (int j = 0; j < 8; ++j)
      v[j] = (short)f2bf(w1[(kc * 32 + 8 * gg + j) * 64 + nt * 16 + cc]);
    w1f[t] = v;
  }
  __syncthreads();

  const int lane = threadIdx.x & 63, wid = threadIdx.x >> 6;
  const int g = lane >> 4, c = lane & 15;
  const long tile = (long)blockIdx.x * 4 + wid;
  const long ebase = tile * 16;

  // ef A-frags (row c = edge, k = kc*32+8g+j), fused ef copy-out
  short8 af[2];
  const float* rowp = ef + (ebase + c) * 64;
#pragma unroll
  for (int kc = 0; kc < 2; ++kc) {
    const f32x4* p = (const f32x4*)(rowp + kc * 32 + 8 * g);
    f32x4 lo = p[0], hi = p[1];
    if (do_copy) {
      f32x4* q = (f32x4*)(efout + (ebase + c) * 64 + kc * 32 + 8 * g);
      q[0] = lo; q[1] = hi;
    }
    short8 v;
#pragma unroll
    for (int j = 0; j < 4; ++j) { v[j] = (short)f2bf(lo[j]); v[4 + j] = (short)f2bf(hi[j]); }
    af[kc] = v;
  }

  f32x4 acc[4] = {};
#pragma unroll
  for (int nt = 0; nt < 4; ++nt)
#pragma unroll
    for (int kc = 0; kc < 2; ++kc)
      acc[nt] = mfma16(af[kc], w1f[(nt * 2 + kc) * 64 + lane], acc[nt]);

  // bias + relu, transpose via LDS (D row=4g+q -> h row-major [edge][feat])
#pragma unroll
  for (int nt = 0; nt < 4; ++nt) {
    float bv = b1[nt * 16 + c];
#pragma unroll
    for (int q = 0; q < 4; ++q) {
      float h = fmaxf(acc[nt][q] + bv, 0.f);
      hlds[wid][(4 * g + q) * 72 + nt * 16 + c] = f2bf(h);
    }
  }
#pragma unroll
  for (int kc = 0; kc < 2; ++kc) {
    short8 hv = *(const short8*)&hlds[wid][c * 72 + kc * 32 + 8 * g];
    hfrag[(tile * 2 + kc) * 64 + lane] = hv;
  }
}

// ---------------- K2: r-specialized MLP2 + tensor product + scatter ----------------
constexpr int BT = 9;                             // 16-edge tiles per batch
constexpr int NBATCH = (10000 + BT - 1) / BT;     // 1112

__global__ __launch_bounds__(576) void conv_kernel(
    const short8* __restrict__ hfrag, const float* __restrict__ w2,
    const float* __restrict__ b2, const float* __restrict__ nf,
    const float* __restrict__ sh, const int* __restrict__ ei,
    float* __restrict__ seg, float* __restrict__ cnt)
{
  __shared__ short8 hbuf[BT * 2 * 64];   // 18.4 KB h-frag batch
  __shared__ float o0[BT][16][17];       // out0 acc tiles (pad 17)
  __shared__ float o1[BT][16][25];       // out1 acc tiles, flat v*3+i (pad 25)

  const int tid = threadIdx.x;
  const int lane = tid & 63, r = tid >> 6;   // wave id == r-group 0..8
  const int g = lane >> 4, c = lane & 15;
  const int gh = g >> 1, gl = g & 1;

  // one-time: this wave's W2^T slice as A-frags (32 VGPR) + bias
  short8 w2f[4][2];
  float b2v[4][4];
#pragma unroll
  for (int jt = 0; jt < 4; ++jt) {
#pragma unroll
    for (int kc = 0; kc < 2; ++kc) {
      short8 v;
#pragma unroll
      for (int j = 0; j < 8; ++j)
        v[j] = (short)f2bf(w2[(kc * 32 + 8 * g + j) * 576 + r * 64 + jt * 16 + c]);
      w2f[jt][kc] = v;
    }
#pragma unroll
    for (int q = 0; q < 4; ++q) b2v[jt][q] = b2[r * 64 + jt * 16 + 4 * g + q];
  }

  for (int t = tid; t < BT * 16 * 17; t += 576) ((float*)o0)[t] = 0.f;
  for (int t = tid; t < BT * 16 * 25; t += 576) ((float*)o1)[t] = 0.f;

  for (int b = blockIdx.x; b < NBATCH; b += gridDim.x) {
    const int tile0 = b * BT;
    const int net = min(BT, 10000 - tile0);
    const int nel = net * 128;

    short8 hr[2];
#pragma unroll
    for (int i = 0; i < 2; ++i) {
      short8 hv = {};
      int el = tid + i * 576;
      if (el < nel) hv = hfrag[tile0 * 128 + el];
      hr[i] = hv;
    }
    __syncthreads();   // A: previous flush done, hbuf free
#pragma unroll
    for (int i = 0; i < 2; ++i) {
      int el = tid + i * 576;
      if (el < nel) hbuf[el] = hr[i];
    }
    __syncthreads();   // B: hbuf ready, acc tiles zeroed

    for (int et = 0; et < net; ++et) {
      const int eg = (tile0 + et) * 16 + c;            // this lane's edge
      const int dst = ei[eg];
      const float* __restrict__ nfd = nf + (long)dst * 40;
      const short8 h0 = hbuf[et * 128 + lane];
      const short8 h1 = hbuf[et * 128 + 64 + lane];

      if (r < 4) {                      // w00: u = 4r+jt, v = 4g+q
        float oa[4] = {0.f, 0.f, 0.f, 0.f};
#pragma unroll
        for (int jt = 0; jt < 4; ++jt) {
          f32x4 a = {b2v[jt][0], b2v[jt][1], b2v[jt][2], b2v[jt][3]};
          a = mfma16(w2f[jt][0], h0, a);
          a = mfma16(w2f[jt][1], h1, a);
          float x0u = nfd[4 * r + jt];
#pragma unroll
          for (int q = 0; q < 4; ++q) oa[q] += x0u * a[q];
        }
        float s0 = ALPHA * sh[eg * 4];
#pragma unroll
        for (int q = 0; q < 4; ++q) atomicAdd(&o0[et][c][4 * g + q], s0 * oa[q]);
      } else if (r < 6) {               // w11: u = (r-4)*4+jt, v = 4g+q
        float s1x = sh[eg * 4 + 1], s1y = sh[eg * 4 + 2], s1z = sh[eg * 4 + 3];
        float oa[4] = {0.f, 0.f, 0.f, 0.f};
#pragma unroll
        for (int jt = 0; jt < 4; ++jt) {
          f32x4 a = {b2v[jt][0], b2v[jt][1], b2v[jt][2], b2v[jt][3]};
          a = mfma16(w2f[jt][0], h0, a);
          a = mfma16(w2f[jt][1], h1, a);
          int u = (r - 4) * 4 + jt;
          float y = nfd[16 + u * 3] * s1x + nfd[16 + u * 3 + 1] * s1y +
                    nfd[16 + u * 3 + 2] * s1z;
#pragma unroll
          for (int q = 0; q < 4; ++q) oa[q] += y * a[q];
        }
#pragma unroll
        for (int q = 0; q < 4; ++q)
          atomicAdd(&o0[et][c][4 * g + q], (ALPHA * INV3) * oa[q]);
      } else if (r < 8) {               // w01: u = (r-6)*8+2jt+gh, v = 4gl+q
        float s1[3] = {sh[eg * 4 + 1], sh[eg * 4 + 2], sh[eg * 4 + 3]};
        float za[4] = {0.f, 0.f, 0.f, 0.f};
#pragma unroll
        for (int jt = 0; jt < 4; ++jt) {
          f32x4 a = {b2v[jt][0], b2v[jt][1], b2v[jt][2], b2v[jt][3]};
          a = mfma16(w2f[jt][0], h0, a);
          a = mfma16(w2f[jt][1], h1, a);
          float x0u = nfd[(r - 6) * 8 + 2 * jt + gh];
#pragma unroll
          for (int q = 0; q < 4; ++q) za[q] += x0u * a[q];
        }
#pragma unroll
        for (int q = 0; q < 4; ++q)
#pragma unroll
          for (int i = 0; i < 3; ++i)
            atomicAdd(&o1[et][c][(4 * gl + q) * 3 + i], ALPHA * s1[i] * za[q]);
      } else {                          // w10: u = 2jt+gh, v = 4gl+q
        float ta[3][4] = {};
#pragma unroll
        for (int jt = 0; jt < 4; ++jt) {
          f32x4 a = {b2v[jt][0], b2v[jt][1], b2v[jt][2], b2v[jt][3]};
          a = mfma16(w2f[jt][0], h0, a);
          a = mfma16(w2f[jt][1], h1, a);
          int u = 2 * jt + gh;
          float x1v[3] = {nfd[16 + u * 3], nfd[16 + u * 3 + 1], nfd[16 + u * 3 + 2]};
#pragma unroll
          for (int i = 0; i < 3; ++i)
#pragma unroll
            for (int q = 0; q < 4; ++q) ta[i][q] += x1v[i] * a[q];
        }
        float s0 = ALPHA * sh[eg * 4];
#pragma unroll
        for (int q = 0; q < 4; ++q)
#pragma unroll
          for (int i = 0; i < 3; ++i)
            atomicAdd(&o1[et][c][(4 * gl + q) * 3 + i], s0 * ta[i][q]);
      }
    }
    __syncthreads();   // C: all LDS adds done
    const int cells = net * 16 * 40;
    for (int t = tid; t < cells; t += 576) {
      int eL = t / 40, ch = t - eL * 40;
      int et = eL >> 4, el = eL & 15;
      float v;
      if (ch < 16) { v = o0[et][el][ch];      o0[et][el][ch] = 0.f; }
      else         { v = o1[et][el][ch - 16]; o1[et][el][ch - 16] = 0.f; }
      int src = ei[NE + tile0 * 16 + eL];
      atomicAdd(seg + (long)src * 40 + ch, v);
    }
    for (int t = tid; t < net * 16; t += 576) {
      int src = ei[NE + tile0 * 16 + t];
      atomicAdd(cnt + src, 1.f);
    }
  }
}

// ---------------- node kernels (unchanged, proven in round 1) ----------------
__global__ __launch_bounds__(256) void node_pass1(
    const float* __restrict__ seg, const float* __restrict__ cnt,
    const float* __restrict__ nf, float* __restrict__ pre,
    float* __restrict__ stats)
{
  __shared__ float ls[40];
  if (threadIdx.x < 40) ls[threadIdx.x] = 0.f;
  __syncthreads();
  int idx = blockIdx.x * blockDim.x + threadIdx.x;
  if (idx < NN * 40) {
    int n = idx / 40;
    int c = idx - n * 40;
    float cn = fmaxf(cnt[n], 1.f);
    float val = seg[idx] / cn + nf[idx];
    pre[idx] = val;
    if (c < 16) {
      atomicAdd(&ls[c], val);
      atomicAdd(&ls[16 + c], val * val);
    } else {
      int u = (c - 16) / 3;
      atomicAdd(&ls[32 + u], val * val);
    }
  }
  __syncthreads();
  if (threadIdx.x < 40) atomicAdd(&stats[threadIdx.x], ls[threadIdx.x]);
}

__global__ __launch_bounds__(256) void node_pass2(
    const float* __restrict__ pre, const float* __restrict__ stats,
    const float* __restrict__ bnws, const float* __restrict__ bnbs,
    const float* __restrict__ bnwv, float* __restrict__ out)
{
  int idx = blockIdx.x * blockDim.x + threadIdx.x;
  if (idx >= NN * 40) return;
  int n = idx / 40;
  int c = idx - n * 40;
  float val = pre[idx];
  constexpr float invN = 1.0f / NN;
  if (c < 16) {
    float mu = stats[c] * invN;
    float var = stats[16 + c] * invN - mu * mu;
    out[idx] = (val - mu) * (rsqrtf(var + EPSV) * bnws[c]) + bnbs[c];
  } else {
    int u = (c - 16) / 3;
    float vn = stats[32 + u] * (invN / 3.0f);
    out[idx] = val * (rsqrtf(vn + EPSV) * bnwv[u]);
  }
}

__global__ __launch_bounds__(256) void copy_ef(const f32x4* __restrict__ src,
                                               f32x4* __restrict__ dst) {
  const int n4 = NE * 64 / 4;
  for (int i = blockIdx.x * blockDim.x + threadIdx.x; i < n4;
       i += gridDim.x * blockDim.x)
    dst[i] = src[i];
}

extern "C" void kernel_launch(void* const* d_in, const int* in_sizes, int n_in,
                              void* d_out, int out_size, void* d_ws, size_t ws_size,
                              hipStream_t stream) {
  (void)in_sizes; (void)n_in; (void)out_size;
  const float* nf   = (const float*)d_in[0];
  const float* ef   = (const float*)d_in[1];
  const float* sh   = (const float*)d_in[2];
  const int*   ei   = (const int*)d_in[3];
  const float* w1   = (const float*)d_in[4];
  const float* b1   = (const float*)d_in[5];
  const float* w2   = (const float*)d_in[6];
  const float* b2   = (const float*)d_in[7];
  const float* bnws = (const float*)d_in[8];
  const float* bnbs = (const float*)d_in[9];
  const float* bnwv = (const float*)d_in[10];

  float* out   = (float*)d_out;
  float* seg   = (float*)d_ws;                 // NN*40
  float* cntb  = seg + (size_t)NN * 40;        // NN
  float* stats = cntb + NN;                    // 40
  float* pre   = stats + 40;                   // NN*40
  float* efout = out + (size_t)NN * 40;

  size_t base_bytes = ((size_t)NN * 40 + NN + 40 + (size_t)NN * 40) * 4;
  size_t hoff = (base_bytes + 255) & ~(size_t)255;
  size_t need = hoff + (size_t)NE * 64 * 2;

  short8* hfrag;
  int do_copy, need_k3;
  if (ws_size >= need) {
    hfrag = (short8*)((char*)d_ws + hoff);
    do_copy = 1; need_k3 = 0;
  } else {  // stash h-frags in the (larger) ef-copy output region, fix up after
    hfrag = (short8*)efout;
    do_copy = 0; need_k3 = 1;
  }

  hipMemsetAsync(d_ws, 0, ((size_t)NN * 40 + NN + 40) * sizeof(float), stream);

  mlp1_kernel<<<2500, 256, 0, stream>>>(ef, w1, b1, hfrag, efout, do_copy);
  conv_kernel<<<512, 576, 0, stream>>>(hfrag, w2, b2, nf, sh, ei, seg, cntb);

  const int nblocks = (NN * 40 + 255) / 256;
  node_pass1<<<nblocks, 256, 0, stream>>>(seg, cntb, nf, pre, stats);
  node_pass2<<<nblocks, 256, 0, stream>>>(pre, stats, bnws, bnbs, bnwv, out);
  if (need_k3) copy_ef<<<2048, 256, 0, stream>>>((const f32x4*)ef, (f32x4*)efout);
}

// Round 3
// 302.813 us; speedup vs baseline: 1.0847x; 1.0847x over previous
//
#include <hip/hip_runtime.h>

typedef __attribute__((ext_vector_type(8))) short short8;
typedef __attribute__((ext_vector_type(4))) float f32x4;

constexpr int NN = 10000;
constexpr int NE = 160000;
constexpr int NT = NE / 16;                    // 10000 edge-tiles
constexpr float EPSV = 1e-5f;
constexpr float INV3 = 0.57735026918962576f;   // 1/sqrt(3)
constexpr float ALPHA = 0.20412414523193152f;  // 1/sqrt(16+8)

__device__ __forceinline__ ushort f2bf(float x) {
  unsigned u = __float_as_uint(x);
  u += 0x7fffu + ((u >> 16) & 1u);   // round-nearest-even
  return (ushort)(u >> 16);
}

__device__ __forceinline__ f32x4 mfma16(short8 a, short8 b, f32x4 c) {
  return __builtin_amdgcn_mfma_f32_16x16x32_bf16(a, b, c, 0, 0, 0);
}

// ---------------- K0: transpose W2 -> bf16 A-frag layout; b2 nonzero flag ----------------
// w2bf[(jt*2+kc)*64 + lane] elem j = bf16( W2[kc*32+8g+j][jt*16+c] ), lane=(g,c)
__global__ __launch_bounds__(64) void prep_w2(const float* __restrict__ w2,
                                              const float* __restrict__ b2,
                                              short8* __restrict__ w2bf,
                                              float* __restrict__ flag) {
  int b = blockIdx.x;
  int lane = threadIdx.x;
  if (b < 72) {
    int jt = b >> 1, kc = b & 1;
    int g = lane >> 4, c = lane & 15;
    short8 v;
#pragma unroll
    for (int j = 0; j < 8; ++j)
      v[j] = (short)f2bf(w2[(kc * 32 + 8 * g + j) * 576 + jt * 16 + c]);
    w2bf[(jt * 2 + kc) * 64 + lane] = v;
  } else {
    float m = 0.f;
    for (int i = lane; i < 576; i += 64) m = fmaxf(m, fabsf(b2[i]));
#pragma unroll
    for (int off = 1; off < 64; off <<= 1) m = fmaxf(m, __shfl_xor(m, off));
    if (lane == 0) *flag = m;
  }
}

// ---------------- K1: h = relu(ef @ W1 + b1) -> bf16 h-fragments (verified r2) ----------------
__global__ __launch_bounds__(256) void mlp1_kernel(
    const float* __restrict__ ef, const float* __restrict__ w1,
    const float* __restrict__ b1, short8* __restrict__ hfrag,
    float* __restrict__ efout, int do_copy)
{
  __shared__ short8 w1f[512];
  __shared__ ushort hlds[4][16 * 72];

  for (int t = threadIdx.x; t < 512; t += 256) {
    int tile = t >> 6, l = t & 63;
    int nt = tile >> 1, kc = tile & 1;
    int gg = l >> 4, cc = l & 15;
    short8 v;
#pragma unroll
    for (int j = 0; j < 8; ++j)
      v[j] = (short)f2bf(w1[(kc * 32 + 8 * gg + j) * 64 + nt * 16 + cc]);
    w1f[t] = v;
  }
  __syncthreads();

  const int lane = threadIdx.x & 63, wid = threadIdx.x >> 6;
  const int g = lane >> 4, c = lane & 15;
  const long tile = (long)blockIdx.x * 4 + wid;
  const long ebase = tile * 16;

  short8 af[2];
  const float* rowp = ef + (ebase + c) * 64;
#pragma unroll
  for (int kc = 0; kc < 2; ++kc) {
    const f32x4* p = (const f32x4*)(rowp + kc * 32 + 8 * g);
    f32x4 lo = p[0], hi = p[1];
    if (do_copy) {
      f32x4* q = (f32x4*)(efout + (ebase + c) * 64 + kc * 32 + 8 * g);
      q[0] = lo; q[1] = hi;
    }
    short8 v;
#pragma unroll
    for (int j = 0; j < 4; ++j) { v[j] = (short)f2bf(lo[j]); v[4 + j] = (short)f2bf(hi[j]); }
    af[kc] = v;
  }

  f32x4 acc[4] = {};
#pragma unroll
  for (int nt = 0; nt < 4; ++nt)
#pragma unroll
    for (int kc = 0; kc < 2; ++kc)
      acc[nt] = mfma16(af[kc], w1f[(nt * 2 + kc) * 64 + lane], acc[nt]);

#pragma unroll
  for (int nt = 0; nt < 4; ++nt) {
    float bv = b1[nt * 16 + c];
#pragma unroll
    for (int q = 0; q < 4; ++q) {
      float h = fmaxf(acc[nt][q] + bv, 0.f);
      hlds[wid][(4 * g + q) * 72 + nt * 16 + c] = f2bf(h);
    }
  }
#pragma unroll
  for (int kc = 0; kc < 2; ++kc) {
    short8 hv = *(const short8*)&hlds[wid][c * 72 + kc * 32 + 8 * g];
    hfrag[(tile * 2 + kc) * 64 + lane] = hv;
  }
}

// ---------------- K2: per-wave 16-edge tile: j-GEMM (72 MFMA) + lane-local TP + scatter ----------------
constexpr int K2_WAVES = 8;
constexpr int K2_GRID = 256;
constexpr int SCR = 52;                                  // f32 per edge scratch row
constexpr unsigned SM_W2 = 4608 * 16;                    // 73728 B: W2 frags
constexpr unsigned SM_B2 = 576 * 4;                      // b2 tables
constexpr unsigned SM_SCRB = K2_WAVES * 16 * SCR * 4;    // 26624 B
constexpr unsigned SM_TOTAL = SM_W2 + SM_B2 + SM_SCRB;   // 102656 B

__global__ __launch_bounds__(512, 1) void conv_kernel(
    const short8* __restrict__ hfrag, const short8* __restrict__ w2bf,
    const float* __restrict__ b2, const float* __restrict__ nf,
    const float* __restrict__ sh, const int* __restrict__ ei,
    float* __restrict__ seg, float* __restrict__ cnt,
    const float* __restrict__ flagp)
{
  extern __shared__ char smem[];
  short8* w2lds = (short8*)smem;
  float* b2t = (float*)(smem + SM_W2);
  float* scrbase = (float*)(smem + SM_W2 + SM_B2);

  const int tid = threadIdx.x;
  for (int i = tid; i < 4608; i += 512) w2lds[i] = w2bf[i];
  const bool hasb2 = (*flagp != 0.f);
  if (hasb2) for (int i = tid; i < 576; i += 512) b2t[i] = b2[i];
  __syncthreads();

  const int lane = tid & 63, wid = tid >> 6;
  const int g = lane >> 4, c = lane & 15;
  const int gh = g >> 1, gl = g & 1;
  float* scr = scrbase + wid * 16 * SCR;

  const int gw = blockIdx.x * K2_WAVES + wid;
  for (int t = gw; t < NT; t += K2_GRID * K2_WAVES) {
    // stage nf rows of the 16 edges into scr[e][0..39]  (x0 = 0..15, x1 flat = 16..39)
    {
      int e = lane >> 2, part = lane & 3;
      int dst = ei[t * 16 + e];
      const float* src = nf + (long)dst * 40;
      f32x4 v0 = *(const f32x4*)(src + part * 4);
      f32x4 v1 = *(const f32x4*)(src + 16 + part * 4);
      *(f32x4*)(scr + e * SCR + part * 4) = v0;
      *(f32x4*)(scr + e * SCR + 16 + part * 4) = v1;
      if (part < 2) {
        f32x4 v2 = *(const f32x4*)(src + 32 + part * 4);
        *(f32x4*)(scr + e * SCR + 32 + part * 4) = v2;
      }
    }
    f32x4 shv = *(const f32x4*)(sh + (long)(t * 16 + c) * 4);
    const float sh0 = shv[0];

    // a1[e][u] = inv3*(x1[e][u]·sh1[e]) -> scr[e][40+u]  (lane e=c computes u=(lane>>4), +4)
    asm volatile("s_waitcnt lgkmcnt(0)" ::: "memory");
    {
      int u0 = lane >> 4;
#pragma unroll
      for (int uu = 0; uu < 2; ++uu) {
        int u = u0 + uu * 4;
        const float* xr = scr + c * SCR + 16 + u * 3;
        scr[c * SCR + 40 + u] = INV3 * (xr[0] * shv[1] + xr[1] * shv[2] + xr[2] * shv[3]);
      }
    }
    asm volatile("s_waitcnt lgkmcnt(0)" ::: "memory");

    // per-lane register preloads (edge = c)
    float a0v[16];   // sh0 * x0[jt]
    {
#pragma unroll
      for (int p = 0; p < 4; ++p) {
        f32x4 r = *(const f32x4*)(scr + c * SCR + p * 4);
#pragma unroll
        for (int j = 0; j < 4; ++j) a0v[p * 4 + j] = sh0 * r[j];
      }
    }
    float a1v[8];    // inv3*(x1·sh1)
    {
      f32x4 r0 = *(const f32x4*)(scr + c * SCR + 40);
      f32x4 r1 = *(const f32x4*)(scr + c * SCR + 44);
#pragma unroll
      for (int j = 0; j < 4; ++j) { a1v[j] = r0[j]; a1v[4 + j] = r1[j]; }
    }
    float x01v[8];   // x0[2jt+gh]
#pragma unroll
    for (int jt = 0; jt < 8; ++jt) x01v[jt] = scr[c * SCR + 2 * jt + gh];
    float x1v[3][4]; // x1[2jt+gh][i]
#pragma unroll
    for (int jt = 0; jt < 4; ++jt)
#pragma unroll
      for (int i = 0; i < 3; ++i)
        x1v[i][jt] = scr[c * SCR + 16 + (2 * jt + gh) * 3 + i];

    const short8 h0 = hfrag[(t * 2 + 0) * 64 + lane];
    const short8 h1 = hfrag[(t * 2 + 1) * 64 + lane];

    f32x4 out0acc = {0.f, 0.f, 0.f, 0.f};
    f32x4 c0acc = {0.f, 0.f, 0.f, 0.f};
    f32x4 c1acc[3] = {};

    if (hasb2) {  // general-correctness path; inactive when b2 == 0
      float bsc = (gh == 0) ? 1.f : 0.f;  // c0/c1 bias only in gh=0 copy (pre-xor32)
#pragma unroll
      for (int u = 0; u < 16; ++u) {
        float x0u = scr[c * SCR + u];
#pragma unroll
        for (int q = 0; q < 4; ++q) {
          out0acc[q] += sh0 * x0u * b2t[u * 16 + 4 * g + q];
          c0acc[q] += bsc * x0u * b2t[384 + u * 8 + 4 * gl + q];
        }
      }
#pragma unroll
      for (int u = 0; u < 8; ++u) {
#pragma unroll
        for (int q = 0; q < 4; ++q) out0acc[q] += a1v[u] * b2t[256 + u * 16 + 4 * g + q];
#pragma unroll
        for (int i = 0; i < 3; ++i) {
          float x1ui = scr[c * SCR + 16 + u * 3 + i];
#pragma unroll
          for (int q = 0; q < 4; ++q)
            c1acc[i][q] += bsc * x1ui * b2t[512 + u * 8 + 4 * gl + q];
        }
      }
    }

    // j-GEMM + lane-local TP consume.  D lane(g,c) reg q = w[edge=t*16+c][j=jt*16+4g+q]
#pragma unroll
    for (int jt = 0; jt < 16; ++jt) {          // w00: u=jt, v=4g+q
      f32x4 d = {0.f, 0.f, 0.f, 0.f};
      d = mfma16(w2lds[(jt * 2 + 0) * 64 + lane], h0, d);
      d = mfma16(w2lds[(jt * 2 + 1) * 64 + lane], h1, d);
#pragma unroll
      for (int q = 0; q < 4; ++q) out0acc[q] += a0v[jt] * d[q];
    }
#pragma unroll
    for (int jt = 16; jt < 24; ++jt) {         // w11: u=jt-16, v=4g+q
      f32x4 d = {0.f, 0.f, 0.f, 0.f};
      d = mfma16(w2lds[(jt * 2 + 0) * 64 + lane], h0, d);
      d = mfma16(w2lds[(jt * 2 + 1) * 64 + lane], h1, d);
#pragma unroll
      for (int q = 0; q < 4; ++q) out0acc[q] += a1v[jt - 16] * d[q];
    }
#pragma unroll
    for (int jt = 24; jt < 32; ++jt) {         // w01: u=2(jt-24)+gh, v=4gl+q
      f32x4 d = {0.f, 0.f, 0.f, 0.f};
      d = mfma16(w2lds[(jt * 2 + 0) * 64 + lane], h0, d);
      d = mfma16(w2lds[(jt * 2 + 1) * 64 + lane], h1, d);
#pragma unroll
      for (int q = 0; q < 4; ++q) c0acc[q] += x01v[jt - 24] * d[q];
    }
#pragma unroll
    for (int jt = 32; jt < 36; ++jt) {         // w10: u=2(jt-32)+gh, v=4gl+q
      f32x4 d = {0.f, 0.f, 0.f, 0.f};
      d = mfma16(w2lds[(jt * 2 + 0) * 64 + lane], h0, d);
      d = mfma16(w2lds[(jt * 2 + 1) * 64 + lane], h1, d);
#pragma unroll
      for (int i = 0; i < 3; ++i)
#pragma unroll
        for (int q = 0; q < 4; ++q) c1acc[i][q] += x1v[i][jt - 32] * d[q];
    }

    // reduce gh halves (lanes g<->g^2)
#pragma unroll
    for (int q = 0; q < 4; ++q) c0acc[q] += __shfl_xor(c0acc[q], 32);
#pragma unroll
    for (int i = 0; i < 3; ++i)
#pragma unroll
      for (int q = 0; q < 4; ++q) c1acc[i][q] += __shfl_xor(c1acc[i][q], 32);

    const int srcn = ei[NE + t * 16 + c];
    float* segp = seg + (long)srcn * 40;
#pragma unroll
    for (int q = 0; q < 4; ++q) atomicAdd(segp + 4 * g + q, ALPHA * out0acc[q]);
    if (g < 2) {
#pragma unroll
      for (int q = 0; q < 4; ++q) {
        int v = 4 * g + q;
#pragma unroll
        for (int i = 0; i < 3; ++i)
          atomicAdd(segp + 16 + v * 3 + i,
                    ALPHA * (shv[1 + i] * c0acc[q] + sh0 * c1acc[i][q]));
      }
    }
    if (lane < 16) atomicAdd(cnt + srcn, 1.f);
  }
}

// ---------------- node kernels (proven) ----------------
__global__ __launch_bounds__(256) void node_pass1(
    const float* __restrict__ seg, const float* __restrict__ cnt,
    const float* __restrict__ nf, float* __restrict__ pre,
    float* __restrict__ stats)
{
  __shared__ float ls[40];
  if (threadIdx.x < 40) ls[threadIdx.x] = 0.f;
  __syncthreads();
  int idx = blockIdx.x * blockDim.x + threadIdx.x;
  if (idx < NN * 40) {
    int n = idx / 40;
    int c = idx - n * 40;
    float cn = fmaxf(cnt[n], 1.f);
    float val = seg[idx] / cn + nf[idx];
    pre[idx] = val;
    if (c < 16) {
      atomicAdd(&ls[c], val);
      atomicAdd(&ls[16 + c], val * val);
    } else {
      int u = (c - 16) / 3;
      atomicAdd(&ls[32 + u], val * val);
    }
  }
  __syncthreads();
  if (threadIdx.x < 40) atomicAdd(&stats[threadIdx.x], ls[threadIdx.x]);
}

__global__ __launch_bounds__(256) void node_pass2(
    const float* __restrict__ pre, const float* __restrict__ stats,
    const float* __restrict__ bnws, const float* __restrict__ bnbs,
    const float* __restrict__ bnwv, float* __restrict__ out)
{
  int idx = blockIdx.x * blockDim.x + threadIdx.x;
  if (idx >= NN * 40) return;
  int n = idx / 40;
  int c = idx - n * 40;
  float val = pre[idx];
  constexpr float invN = 1.0f / NN;
  if (c < 16) {
    float mu = stats[c] * invN;
    float var = stats[16 + c] * invN - mu * mu;
    out[idx] = (val - mu) * (rsqrtf(var + EPSV) * bnws[c]) + bnbs[c];
  } else {
    int u = (c - 16) / 3;
    float vn = stats[32 + u] * (invN / 3.0f);
    out[idx] = val * (rsqrtf(vn + EPSV) * bnwv[u]);
  }
}

__global__ __launch_bounds__(256) void copy_ef(const f32x4* __restrict__ src,
                                               f32x4* __restrict__ dst) {
  const int n4 = NE * 64 / 4;
  for (int i = blockIdx.x * blockDim.x + threadIdx.x; i < n4;
       i += gridDim.x * blockDim.x)
    dst[i] = src[i];
}

extern "C" void kernel_launch(void* const* d_in, const int* in_sizes, int n_in,
                              void* d_out, int out_size, void* d_ws, size_t ws_size,
                              hipStream_t stream) {
  (void)in_sizes; (void)n_in; (void)out_size;
  const float* nf   = (const float*)d_in[0];
  const float* ef   = (const float*)d_in[1];
  const float* sh   = (const float*)d_in[2];
  const int*   ei   = (const int*)d_in[3];
  const float* w1   = (const float*)d_in[4];
  const float* b1   = (const float*)d_in[5];
  const float* w2   = (const float*)d_in[6];
  const float* b2   = (const float*)d_in[7];
  const float* bnws = (const float*)d_in[8];
  const float* bnbs = (const float*)d_in[9];
  const float* bnwv = (const float*)d_in[10];

  float* out   = (float*)d_out;
  float* seg   = (float*)d_ws;                  // NN*40
  float* cntb  = seg + (size_t)NN * 40;         // NN
  float* stats = cntb + NN;                     // 40 + flag(8 pad)
  float* flag  = stats + 40;
  float* pre   = stats + 48;                    // NN*40
  float* efout = out + (size_t)NN * 40;

  size_t base_f32 = (size_t)NN * 40 + NN + 48 + (size_t)NN * 40;
  size_t w2off = (base_f32 * 4 + 255) & ~(size_t)255;
  short8* w2bf = (short8*)((char*)d_ws + w2off);
  size_t hoff = (w2off + SM_W2 + 255) & ~(size_t)255;
  size_t need = hoff + (size_t)NE * 64 * 2;

  short8* hfrag;
  int do_copy, need_k3;
  if (ws_size >= need) {
    hfrag = (short8*)((char*)d_ws + hoff);
    do_copy = 1; need_k3 = 0;
  } else {  // stash h-frags in the ef-copy output region; real copy afterwards
    hfrag = (short8*)efout;
    do_copy = 0; need_k3 = 1;
  }

  hipMemsetAsync(d_ws, 0, ((size_t)NN * 40 + NN + 48) * sizeof(float), stream);

  hipFuncSetAttribute((const void*)conv_kernel,
                      hipFuncAttributeMaxDynamicSharedMemorySize, SM_TOTAL);

  prep_w2<<<73, 64, 0, stream>>>(w2, b2, w2bf, flag);
  mlp1_kernel<<<2500, 256, 0, stream>>>(ef, w1, b1, hfrag, efout, do_copy);
  conv_kernel<<<K2_GRID, 512, SM_TOTAL, stream>>>(hfrag, w2bf, b2, nf, sh, ei,
                                                  seg, cntb, flag);

  const int nblocks = (NN * 40 + 255) / 256;
  node_pass1<<<nblocks, 256, 0, stream>>>(seg, cntb, nf, pre, stats);
  node_pass2<<<nblocks, 256, 0, stream>>>(pre, stats, bnws, bnbs, bnwv, out);
  if (need_k3) copy_ef<<<2048, 256, 0, stream>>>((const f32x4*)ef, (f32x4*)efout);
}